// Round 2
// baseline (90.937 us; speedup 1.0000x reference)
//
#include <hip/hip_runtime.h>
#include <hip/hip_bf16.h>

#define EPSF 1e-7f
#define B_ 8
#define H_ 64
#define W_ 64
#define C_ 32
#define HO 58
#define WO 58
#define NF 64
#define KDIM 800

#define XTS 36      // xt padded channel stride (floats): 16B-aligned, bank spread
#define RPS 520     // rot pos-stride in bf16 units (16*32 + 8): 16B-aligned, bank spread

typedef __bf16 v8bf __attribute__((ext_vector_type(8)));
typedef float  v4f  __attribute__((ext_vector_type(4)));

// ---- pack W into MFMA B-fragment order, bf16 ----
// Wp[((nt*25+kb)*64+lane)*8+j] = W[f=nt*16+(lane&15)][k=kb*32+(lane>>4)*8+j]
__global__ void k_wpack(const float* __restrict__ W, __bf16* __restrict__ Wp) {
    int t = blockIdx.x*256 + threadIdx.x;   // 51200 total
    int j = t & 7; int lane = (t >> 3) & 63; int rest = t >> 9;
    int kb = rest % 25; int nt = rest / 25;
    int f = nt*16 + (lane & 15);
    int k = kb*32 + (lane >> 4)*8 + j;
    Wp[t] = (__bf16)W[f*KDIM + k];
}

// ---- fully fused: stage -> intensity -> angle -> rotate -> MFMA ----
__global__ __launch_bounds__(256)
void k_main(const float* __restrict__ x, const v8bf* __restrict__ Wp,
            const float* __restrict__ bias, float* __restrict__ out) {
    __shared__ float  xt[7][22][XTS];     // 22,176 B
    __shared__ __bf16 rot[25*RPS];        // 26,000 B
    __shared__ float  Srow[7][22];
    __shared__ float4 pp[16];

    int tid = threadIdx.x;
    int wv = tid >> 6, lane = tid & 63;
    int wt = blockIdx.x, ho = blockIdx.y, b = blockIdx.z;
    int wo0 = wt*16;
    int npx = WO - wo0; if (npx > 16) npx = 16;   // 16,16,16,10
    int ncols = npx + 6;

    // hoisted B-fragment loads: latency/L2-BW overlapped with phases 0-3
    v8bf bfrag[25];
    {
        const v8bf* wp = Wp + (size_t)wv*25*64 + lane;
#pragma unroll
        for (int kb = 0; kb < 25; kb++) bfrag[kb] = wp[kb*64];
    }

    // phase 0: stage x tile (rows ho..ho+6, cols wo0..wo0+ncols-1, 32 ch)
    const float* xb = x + (size_t)((b*H_ + ho)*W_ + wo0)*C_;
    int total4 = 7*ncols*8;
    for (int e = tid; e < total4; e += 256) {
        int r = e/(ncols*8); int rem = e - r*(ncols*8);
        int c = rem >> 3;    int q = rem & 7;
        *(float4*)&xt[r][c][q*4] = *(const float4*)&xb[(r*W_ + c)*C_ + q*4];
    }
    __syncthreads();

    // phase 1: per-(row,col) channel sums
    if (tid < 7*ncols) {
        int r = tid / ncols, c = tid - r*ncols;
        float s = 0.f;
#pragma unroll
        for (int q = 0; q < 8; q++) {
            float4 v = *(const float4*)&xt[r][c][q*4];
            s += v.x + v.y + v.z + v.w;
        }
        Srow[r][c] = s;
    }
    __syncthreads();

    // phase 2: per-pixel affine params
    if (tid < npx) {
        float den = 0.f, crn = 0.f, ccn = 0.f;
#pragma unroll
        for (int i = 0; i < 7; i++)
#pragma unroll
            for (int j = 0; j < 7; j++) {
                float v = Srow[i][tid + j];
                den += v; crn += v*(float)i; ccn += v*(float)j;
            }
        float dt = den + EPSF;
        float cr = crn/dt - 3.0f;
        float cc = ccn/dt - 3.0f;
        float ang = atan2f(cr, cc + EPSF);
        float c = cosf(ang), s = sinf(ang);
        const float scale = 1.0f + EPSF;
        float xo = (6.0f - (c*6.0f - s*6.0f))*0.5f;
        float yo = (6.0f - (s*6.0f + c*6.0f))*0.5f;
        pp[tid] = make_float4(c/scale, s/scale, xo/scale, yo/scale);
    }
    __syncthreads();

    // phase 3: one thread per (px,pos), all 32 channels; affine computed once
    int tot = npx*25;
    for (int e = tid; e < tot; e += 256) {
        int px = e/25; int pos = e - px*25;
        int py = pos/5; int yy = py + 1; int xx = pos - py*5 + 1;
        float4 p = pp[px];
        float xin = p.x*(float)xx - p.y*(float)yy + p.z;
        float yin = p.y*(float)xx + p.x*(float)yy + p.w;
        float x0f = floorf(xin), y0f = floorf(yin);
        float wx1 = xin - x0f, wx0 = 1.0f - wx1;
        float wy1 = yin - y0f, wy0 = 1.0f - wy1;
        int ix0 = (int)x0f, iy0 = (int)y0f;
        int ix1 = ix0 + 1,  iy1 = iy0 + 1;

        const float* bp[4]; float wgt[4];
        auto mkcorner = [&](int yi, int xi, float w, int idx) {
            bool valid = (xi >= 0) & (xi < 7) & (yi >= 0) & (yi < 7);
            int cy = yi < 0 ? 0 : (yi > 6 ? 6 : yi);
            int cx = xi < 0 ? 0 : (xi > 6 ? 6 : xi);
            bp[idx]  = &xt[cy][px + cx][0];
            wgt[idx] = valid ? w : 0.0f;
        };
        mkcorner(iy0, ix0, wy0*wx0, 0);
        mkcorner(iy0, ix1, wy0*wx1, 1);
        mkcorner(iy1, ix0, wy1*wx0, 2);
        mkcorner(iy1, ix1, wy1*wx1, 3);

        float acc[32];
#pragma unroll
        for (int ch = 0; ch < 32; ch++) acc[ch] = 0.f;
#pragma unroll
        for (int cn = 0; cn < 4; cn++) {
            const float* src = bp[cn]; float wq = wgt[cn];
#pragma unroll
            for (int q = 0; q < 8; q++) {
                float4 v = *(const float4*)(src + q*4);
                acc[q*4+0] += wq*v.x; acc[q*4+1] += wq*v.y;
                acc[q*4+2] += wq*v.z; acc[q*4+3] += wq*v.w;
            }
        }
        __bf16* dst = &rot[pos*RPS + px*32];
#pragma unroll
        for (int q8 = 0; q8 < 4; q8++) {
            v8bf o;
#pragma unroll
            for (int j = 0; j < 8; j++) o[j] = (__bf16)acc[q8*8 + j];
            *(v8bf*)&dst[q8*8] = o;
        }
    }
    __syncthreads();

    // phase 4: MFMA, 16 px x 16 filters per wave, K=800
    int m = lane & 15, q = lane >> 4;
    v4f acc4 = {0.f, 0.f, 0.f, 0.f};
#pragma unroll
    for (int kb = 0; kb < 25; kb++) {
        v8bf a = *(const v8bf*)&rot[kb*RPS + m*32 + q*8];
        acc4 = __builtin_amdgcn_mfma_f32_16x16x32_bf16(a, bfrag[kb], acc4, 0, 0, 0);
    }
    int f = wv*16 + m;          // C/D col = lane&15 -> filter
    float bv = bias[f];
    int pixbase = (b*HO + ho)*WO + wo0;
#pragma unroll
    for (int r = 0; r < 4; r++) {
        int px = q*4 + r;       // C/D row = (lane>>4)*4 + reg -> pixel
        if (px < npx) out[(size_t)(pixbase + px)*NF + f] = acc4[r] + bv;
    }
}

extern "C" void kernel_launch(void* const* d_in, const int* in_sizes, int n_in,
                              void* d_out, int out_size, void* d_ws, size_t ws_size,
                              hipStream_t stream) {
    const float* x    = (const float*)d_in[0];
    const float* W    = (const float*)d_in[1];
    const float* bias = (const float*)d_in[2];
    float* out = (float*)d_out;
    __bf16* Wp = (__bf16*)d_ws;                    // 102,400 B

    k_wpack<<<dim3(200), 256, 0, stream>>>(W, Wp);
    k_main<<<dim3(4, HO, B_), 256, 0, stream>>>(x, (const v8bf*)Wp, bias, out);
}